// Round 1
// baseline (198.974 us; speedup 1.0000x reference)
//
#include <hip/hip_runtime.h>
#include <math.h>

// Problem constants (from reference setup_inputs): B=256, S=4096, V=30
#define B_DIM 256
#define S_DIM 4096
#define V_DIM 30
#define BS_TOTAL (B_DIM * S_DIM)          // 1,048,576 positions
#define POS_PER_BLOCK 512                 // positions staged per block
#define THREADS 256
#define F4_PER_TILE ((POS_PER_BLOCK * V_DIM) / 4)   // 3840 float4
#define F4_ITERS (F4_PER_TILE / THREADS)            // 15

// Main kernel: per-position argmax + masked NLL accumulation.
// Each block stages a 512x30 fp32 tile into LDS with coalesced float4 loads
// (tile base = blockIdx.x * 512 * 120 B, always 16B-aligned), then each
// thread processes 2 positions from LDS (row stride 30 -> 2-way bank
// aliasing, free on gfx950).
__global__ __launch_bounds__(THREADS) void mlm_main_kernel(
    const float* __restrict__ logits,   // [BS_TOTAL, V_DIM]
    const int*   __restrict__ targets,  // [BS_TOTAL]
    float*       __restrict__ preds,    // [BS_TOTAL] (argmax as float)
    float*       __restrict__ acc)      // [1] global NLL accumulator
{
    __shared__ float tile[POS_PER_BLOCK * V_DIM];   // 61440 B
    __shared__ float wave_sums[THREADS / 64];

    const int t = threadIdx.x;
    const long long base_pos = (long long)blockIdx.x * POS_PER_BLOCK;

    // ---- Stage global -> LDS, fully coalesced 16B/lane ----
    const float4* gsrc  = (const float4*)(logits + base_pos * V_DIM);
    float4*       ltile = (float4*)tile;
#pragma unroll
    for (int k = 0; k < F4_ITERS; ++k) {
        ltile[t + k * THREADS] = gsrc[t + k * THREADS];
    }
    __syncthreads();

    // ---- Per-position argmax + log-softmax NLL ----
    float local_nll = 0.0f;
#pragma unroll
    for (int p = 0; p < POS_PER_BLOCK / THREADS; ++p) {
        const int pos = t + p * THREADS;
        const float* row = &tile[pos * V_DIM];

        float best = row[0];
        int   bidx = 0;
#pragma unroll
        for (int j = 1; j < V_DIM; ++j) {
            float x = row[j];
            if (x > best) { best = x; bidx = j; }   // strict > => first-occurrence argmax
        }

        float s = 0.0f;
#pragma unroll
        for (int j = 0; j < V_DIM; ++j) {
            s += __expf(row[j] - best);
        }

        const long long gpos = base_pos + pos;
        const int tgt = targets[gpos];
        // nll = logsumexp(x) - x[tgt] = (best + log s) - x[tgt]
        if (tgt != 0) {                 // PAD_INDEX == 0 masked out
            local_nll += __logf(s) + best - row[tgt];
        }
        preds[gpos] = (float)bidx;
    }

    // ---- Block reduction of local_nll, one atomicAdd per block ----
#pragma unroll
    for (int off = 32; off > 0; off >>= 1) {
        local_nll += __shfl_down(local_nll, off, 64);
    }
    const int wid  = t >> 6;
    const int lane = t & 63;
    if (lane == 0) wave_sums[wid] = local_nll;
    __syncthreads();
    if (t == 0) {
        float blk = 0.0f;
#pragma unroll
        for (int w = 0; w < THREADS / 64; ++w) blk += wave_sums[w];
        atomicAdd(acc, blk);
    }
}

// Finalize: NSP argmax (B=256 rows of 2) + loss = acc / (B*S).
__global__ __launch_bounds__(B_DIM) void finalize_kernel(
    const float* __restrict__ nsp,       // [B_DIM, 2]
    const float* __restrict__ acc,       // [1]
    float*       __restrict__ out_nsp,   // [B_DIM]
    float*       __restrict__ out_loss)  // [1]
{
    const int b = threadIdx.x;
    const float a0 = nsp[b * 2 + 0];
    const float a1 = nsp[b * 2 + 1];
    out_nsp[b] = (a1 > a0) ? 1.0f : 0.0f;   // strict > => first-occurrence argmax
    if (b == 0) {
        out_loss[0] = acc[0] / (float)BS_TOTAL;
    }
}

extern "C" void kernel_launch(void* const* d_in, const int* in_sizes, int n_in,
                              void* d_out, int out_size, void* d_ws, size_t ws_size,
                              hipStream_t stream) {
    // Inputs (setup_inputs order):
    //   0: mlm_outputs   [256,4096,30] fp32
    //   1: nsp_outputs   [256,2]       fp32
    //   2: mutation_matrix [30,30]     fp32   (weight cancels -> unused)
    //   3: mlm_targets   [256,4096]    int32
    //   4: is_nexts      [256]         int32  (unused by reference loss)
    const float* mlm     = (const float*)d_in[0];
    const float* nsp     = (const float*)d_in[1];
    const int*   targets = (const int*)  d_in[3];

    float* out      = (float*)d_out;
    float* preds    = out;                       // [1048576]
    float* out_nsp  = out + BS_TOTAL;            // [256]
    float* out_loss = out + BS_TOTAL + B_DIM;    // [1]

    float* acc = (float*)d_ws;                   // scratch accumulator
    hipMemsetAsync(acc, 0, sizeof(float), stream);

    const int grid = BS_TOTAL / POS_PER_BLOCK;   // 2048 blocks
    mlm_main_kernel<<<grid, THREADS, 0, stream>>>(mlm, targets, preds, acc);
    finalize_kernel<<<1, B_DIM, 0, stream>>>(nsp, acc, out_nsp, out_loss);
}

// Round 2
// 193.190 us; speedup vs baseline: 1.0299x; 1.0299x over previous
//
#include <hip/hip_runtime.h>
#include <math.h>

// Problem constants (from reference setup_inputs): B=256, S=4096, V=30
#define B_DIM 256
#define S_DIM 4096
#define V_DIM 30
#define BS_TOTAL (B_DIM * S_DIM)          // 1,048,576 positions
#define POS_PER_BLOCK 256                 // 256x30 fp32 tile = 30720 B LDS
#define THREADS 256                       // -> 5 blocks/CU (LDS-bound), 20 waves/CU
#define GRID (BS_TOTAL / POS_PER_BLOCK)   // 4096 blocks
#define F4_PER_TILE ((POS_PER_BLOCK * V_DIM) / 4)   // 1920 float4 (7.5 per thread)

// Per-position argmax + masked NLL. Each block stages a 256x30 tile into LDS
// with coalesced float4 loads (tile base = blockIdx.x*256*120 B, 16B-aligned),
// then each thread processes exactly one row: float2 LDS reads (rows are
// 8B-aligned: 120*p % 8 == 0), register-resident values, target capture via
// selects (no indexed LDS re-read). Deterministic per-block partial sums to
// d_ws — no atomics, no accumulator memset dispatch.
__global__ __launch_bounds__(THREADS) void mlm_main_kernel(
    const float* __restrict__ logits,    // [BS_TOTAL, V_DIM]
    const int*   __restrict__ targets,   // [BS_TOTAL]
    float*       __restrict__ preds,     // [BS_TOTAL] (argmax as float)
    float*       __restrict__ partials)  // [GRID] per-block NLL sums
{
    __shared__ float tile[POS_PER_BLOCK * V_DIM];   // 30720 B
    __shared__ float wave_sums[THREADS / 64];

    const int t = threadIdx.x;
    const int base_pos = blockIdx.x * POS_PER_BLOCK;

    // ---- Stage global -> LDS, fully coalesced 16B/lane (1920 = 7.5*256) ----
    const float4* gsrc  = (const float4*)(logits + (size_t)base_pos * V_DIM);
    float4*       ltile = (float4*)tile;
#pragma unroll
    for (int k = 0; k < 7; ++k) {
        ltile[t + k * THREADS] = gsrc[t + k * THREADS];
    }
    if (t < F4_PER_TILE - 7 * THREADS) {            // last half-iteration (128)
        ltile[t + 7 * THREADS] = gsrc[t + 7 * THREADS];
    }
    __syncthreads();

    // ---- One row per thread: argmax + log-softmax NLL ----
    float vals[V_DIM];
    const float2* row2 = (const float2*)(tile + t * V_DIM);  // 8B-aligned
#pragma unroll
    for (int j = 0; j < V_DIM / 2; ++j) {
        const float2 u = row2[j];
        vals[2 * j]     = u.x;
        vals[2 * j + 1] = u.y;
    }

    float best = vals[0];
    int   bidx = 0;
#pragma unroll
    for (int j = 1; j < V_DIM; ++j) {
        if (vals[j] > best) { best = vals[j]; bidx = j; }   // strict > => first-occurrence
    }

    float s = 0.0f;
#pragma unroll
    for (int j = 0; j < V_DIM; ++j) {
        s += __expf(vals[j] - best);
    }

    const int gpos = base_pos + t;
    const int tgt  = targets[gpos];

    float tv = 0.0f;                                 // vals[tgt] via selects
#pragma unroll
    for (int j = 0; j < V_DIM; ++j) {
        tv = (j == tgt) ? vals[j] : tv;
    }

    const float nll = (tgt != 0) ? (__logf(s) + best - tv) : 0.0f;  // PAD==0 masked
    preds[gpos] = (float)bidx;

    // ---- Block reduction -> partials[blockIdx.x] (deterministic, no atomic) ----
    float r = nll;
#pragma unroll
    for (int off = 32; off > 0; off >>= 1) {
        r += __shfl_down(r, off, 64);
    }
    if ((t & 63) == 0) wave_sums[t >> 6] = r;
    __syncthreads();
    if (t == 0) {
        partials[blockIdx.x] =
            wave_sums[0] + wave_sums[1] + wave_sums[2] + wave_sums[3];
    }
}

// Finalize: NSP argmax (256 rows of 2) + reduce 4096 partials -> loss.
__global__ __launch_bounds__(256) void finalize_kernel(
    const float* __restrict__ nsp,       // [B_DIM, 2]
    const float* __restrict__ partials,  // [GRID]
    float*       __restrict__ out_nsp,   // [B_DIM]
    float*       __restrict__ out_loss)  // [1]
{
    const int t = threadIdx.x;

    const float a0 = nsp[2 * t + 0];
    const float a1 = nsp[2 * t + 1];
    out_nsp[t] = (a1 > a0) ? 1.0f : 0.0f;   // strict > => first-occurrence argmax

    float s = 0.0f;
#pragma unroll
    for (int i = 0; i < GRID / 256; ++i) {  // 16 per thread
        s += partials[t + i * 256];
    }
#pragma unroll
    for (int off = 32; off > 0; off >>= 1) {
        s += __shfl_down(s, off, 64);
    }
    __shared__ float ws[4];
    if ((t & 63) == 0) ws[t >> 6] = s;
    __syncthreads();
    if (t == 0) {
        out_loss[0] = (ws[0] + ws[1] + ws[2] + ws[3]) / (float)BS_TOTAL;
    }
}

extern "C" void kernel_launch(void* const* d_in, const int* in_sizes, int n_in,
                              void* d_out, int out_size, void* d_ws, size_t ws_size,
                              hipStream_t stream) {
    // Inputs (setup_inputs order):
    //   0: mlm_outputs     [256,4096,30] fp32
    //   1: nsp_outputs     [256,2]       fp32
    //   2: mutation_matrix [30,30]       fp32  (weight cancels -> unused)
    //   3: mlm_targets     [256,4096]    int32
    //   4: is_nexts        [256]         int32 (unused by reference loss)
    const float* mlm     = (const float*)d_in[0];
    const float* nsp     = (const float*)d_in[1];
    const int*   targets = (const int*)  d_in[3];

    float* out      = (float*)d_out;
    float* preds    = out;                       // [1048576]
    float* out_nsp  = out + BS_TOTAL;            // [256]
    float* out_loss = out + BS_TOTAL + B_DIM;    // [1]

    float* partials = (float*)d_ws;              // [GRID] — fully overwritten each call

    mlm_main_kernel<<<GRID, THREADS, 0, stream>>>(mlm, targets, preds, partials);
    finalize_kernel<<<1, 256, 0, stream>>>(nsp, partials, out_nsp, out_loss);
}